// Round 6
// baseline (4266.885 us; speedup 1.0000x reference)
//
#include <hip/hip_runtime.h>
#include <cmath>

#define B_ 64
#define T_ 512
#define E_ 512
#define H_ 1024
#define O_ 512
#define BH (B_ * H_)

typedef unsigned short ushort_t;
typedef __bf16 bf16x8 __attribute__((ext_vector_type(8)));
typedef float f32x4 __attribute__((ext_vector_type(4)));

__device__ __forceinline__ ushort_t f2bf(float f) {
    union { float f; unsigned int u; } x; x.f = f;
    unsigned int r = x.u + 0x7fffu + ((x.u >> 16) & 1u);
    return (ushort_t)(r >> 16);
}
__device__ __forceinline__ float bf2f(ushort_t u) {
    union { unsigned int u; float f; } x; x.u = ((unsigned int)u) << 16;
    return x.f;
}
__device__ __forceinline__ uint4 pack8bf(float4 v0, float4 v1) {
    uint4 pk;
    pk.x = (unsigned)f2bf(v0.x) | ((unsigned)f2bf(v0.y) << 16);
    pk.y = (unsigned)f2bf(v0.z) | ((unsigned)f2bf(v0.w) << 16);
    pk.z = (unsigned)f2bf(v1.x) | ((unsigned)f2bf(v1.y) << 16);
    pk.w = (unsigned)f2bf(v1.z) | ((unsigned)f2bf(v1.w) << 16);
    return pk;
}
__device__ __forceinline__ bf16x8 pack8(const float* src) {
    float4 v0 = *(const float4*)src;
    float4 v1 = *(const float4*)(src + 4);
    union { uint4 u; bf16x8 b; } c;
    c.u = pack8bf(v0, v1);
    return c.b;
}
// tagged-word helpers: word = (bf16 << 16) | tag16
__device__ __forceinline__ unsigned tagx(uint4 x, unsigned e) {
    return (x.x ^ e) | (x.y ^ e) | (x.z ^ e) | (x.w ^ e);
}
__device__ __forceinline__ bf16x8 hi8(uint4 lo, uint4 hi) {
    union { unsigned u[4]; bf16x8 b; } r;
    r.u[0] = (lo.x >> 16) | (lo.y & 0xffff0000u);
    r.u[1] = (lo.z >> 16) | (lo.w & 0xffff0000u);
    r.u[2] = (hi.x >> 16) | (hi.y & 0xffff0000u);
    r.u[3] = (hi.z >> 16) | (hi.w & 0xffff0000u);
    return r.b;
}

// ---------------------------------------------------------------- prep ------
// Zero flags; zero exchange parities 0..2; seed parity 3 = epoch -1 (hinit,
// tag 0). 256x256 = 65536 threads.
__global__ void prep_kernel(const float* __restrict__ h0,
                            unsigned* __restrict__ h0ex, unsigned* __restrict__ h1ex,
                            int* __restrict__ bar) {
    int i = blockIdx.x * blockDim.x + threadIdx.x;
    if (i < 32768) bar[i] = 0;
    h0ex[i] = 0; h0ex[BH + i] = 0; h0ex[2 * BH + i] = 0;
    h1ex[i] = 0; h1ex[BH + i] = 0; h1ex[2 * BH + i] = 0;
    h0ex[3 * BH + i] = ((unsigned)f2bf(h0[i])) << 16;
    h1ex[3 * BH + i] = ((unsigned)f2bf(h0[BH + i])) << 16;
}

// ------------------------------------------------ big GEMM: C = A*W^T + b ---
template <int MODE>
__launch_bounds__(256)
__global__ void gemm_bt(const void* __restrict__ Ap, const float* __restrict__ Wp,
                        const float* __restrict__ bias, void* __restrict__ outp,
                        int N, int K) {
    __shared__ __align__(16) ushort_t As[128 * 72];
    __shared__ __align__(16) ushort_t Bs[128 * 72];
    const int tid = threadIdx.x;
    const int lane = tid & 63;
    const int w = tid >> 6;
    const int wm = (w >> 1) * 64;
    const int wn = (w & 1) * 64;
    const int q = lane >> 4;
    const int l16 = lane & 15;
    const int m0 = blockIdx.y * 128;
    const int n0 = blockIdx.x * 128;

    const float*    Af = (const float*)Ap;
    const ushort_t* Ab = (const ushort_t*)Ap;

    f32x4 zero = {0.f, 0.f, 0.f, 0.f};
    f32x4 acc[4][4];
#pragma unroll
    for (int i = 0; i < 4; i++)
#pragma unroll
        for (int j = 0; j < 4; j++) acc[i][j] = zero;

    for (int k0 = 0; k0 < K; k0 += 64) {
#pragma unroll
        for (int it = 0; it < 4; it++) {
            int task = tid + it * 256;
            int row = task >> 3, seg = task & 7;
            if (MODE == 0) {
                int Ra = m0 + row;
                const float* src = Af + (size_t)((Ra & 63) * T_ + (Ra >> 6)) * K + k0 + seg * 8;
                float4 v0 = *(const float4*)src;
                float4 v1 = *(const float4*)(src + 4);
                *(uint4*)&As[row * 72 + seg * 8] = pack8bf(v0, v1);
            } else {
                const ushort_t* src = Ab + (size_t)(m0 + row) * K + k0 + seg * 8;
                *(uint4*)&As[row * 72 + seg * 8] = *(const uint4*)src;
            }
            const float* wsrc = Wp + (size_t)(n0 + row) * K + k0 + seg * 8;
            float4 w0 = *(const float4*)wsrc;
            float4 w1 = *(const float4*)(wsrc + 4);
            *(uint4*)&Bs[row * 72 + seg * 8] = pack8bf(w0, w1);
        }
        __syncthreads();
#pragma unroll
        for (int ks = 0; ks < 64; ks += 32) {
            bf16x8 af[4], bfr[4];
#pragma unroll
            for (int i = 0; i < 4; i++)
                af[i] = *(const bf16x8*)&As[(wm + i * 16 + l16) * 72 + ks + q * 8];
#pragma unroll
            for (int j = 0; j < 4; j++)
                bfr[j] = *(const bf16x8*)&Bs[(wn + j * 16 + l16) * 72 + ks + q * 8];
#pragma unroll
            for (int i = 0; i < 4; i++)
#pragma unroll
                for (int j = 0; j < 4; j++)
                    acc[i][j] = __builtin_amdgcn_mfma_f32_16x16x32_bf16(af[i], bfr[j], acc[i][j], 0, 0, 0);
        }
        __syncthreads();
    }

#pragma unroll
    for (int j = 0; j < 4; j++) {
        int C = n0 + wn + j * 16 + l16;
        float bv = bias[C];
#pragma unroll
        for (int i = 0; i < 4; i++) {
#pragma unroll
            for (int r = 0; r < 4; r++) {
                int R = m0 + wm + i * 16 + q * 4 + r;
                float v = acc[i][j][r] + bv;
                if (MODE == 2) {
                    ((float*)outp)[(size_t)((R & 63) * T_ + (R >> 6)) * N + C] = v;
                } else {
                    ((ushort_t*)outp)[(size_t)R * N + C] = f2bf(v);
                }
            }
        }
    }
}

// 16 tagged-f32 dwordx4 loads (one MFMA A/B operand set for one wave's
// K-slice), verify tags, retry until consistent. Returns frags in fr[8].
__device__ __forceinline__ void load_verify16(const unsigned* base, unsigned exp,
                                              bf16x8 fr[8]) {
    uint4 a0, a1, a2, a3, a4, a5, a6, a7, a8, a9, aa, ab, ac, ad, ae, af;
    for (int t = 0; ; ++t) {
        asm volatile(
            "global_load_dwordx4 %0, %16, off sc0 sc1\n\t"
            "global_load_dwordx4 %1, %16, off offset:16 sc0 sc1\n\t"
            "global_load_dwordx4 %2, %16, off offset:128 sc0 sc1\n\t"
            "global_load_dwordx4 %3, %16, off offset:144 sc0 sc1\n\t"
            "global_load_dwordx4 %4, %16, off offset:256 sc0 sc1\n\t"
            "global_load_dwordx4 %5, %16, off offset:272 sc0 sc1\n\t"
            "global_load_dwordx4 %6, %16, off offset:384 sc0 sc1\n\t"
            "global_load_dwordx4 %7, %16, off offset:400 sc0 sc1\n\t"
            "global_load_dwordx4 %8, %16, off offset:512 sc0 sc1\n\t"
            "global_load_dwordx4 %9, %16, off offset:528 sc0 sc1\n\t"
            "global_load_dwordx4 %10, %16, off offset:640 sc0 sc1\n\t"
            "global_load_dwordx4 %11, %16, off offset:656 sc0 sc1\n\t"
            "global_load_dwordx4 %12, %16, off offset:768 sc0 sc1\n\t"
            "global_load_dwordx4 %13, %16, off offset:784 sc0 sc1\n\t"
            "global_load_dwordx4 %14, %16, off offset:896 sc0 sc1\n\t"
            "global_load_dwordx4 %15, %16, off offset:912 sc0 sc1\n\t"
            "s_waitcnt vmcnt(0)"
            : "=&v"(a0), "=&v"(a1), "=&v"(a2), "=&v"(a3), "=&v"(a4), "=&v"(a5),
              "=&v"(a6), "=&v"(a7), "=&v"(a8), "=&v"(a9), "=&v"(aa), "=&v"(ab),
              "=&v"(ac), "=&v"(ad), "=&v"(ae), "=&v"(af)
            : "v"(base) : "memory");
        unsigned bad = (tagx(a0, exp) | tagx(a1, exp) | tagx(a2, exp) | tagx(a3, exp) |
                        tagx(a4, exp) | tagx(a5, exp) | tagx(a6, exp) | tagx(a7, exp) |
                        tagx(a8, exp) | tagx(a9, exp) | tagx(aa, exp) | tagx(ab, exp) |
                        tagx(ac, exp) | tagx(ad, exp) | tagx(ae, exp) | tagx(af, exp)) & 0xffffu;
        if (__ballot(bad == 0) == ~0ull) break;
        if (t > 1024) break;  // watchdog: wrong data, not a hang
    }
    fr[0] = hi8(a0, a1); fr[1] = hi8(a2, a3); fr[2] = hi8(a4, a5); fr[3] = hi8(a6, a7);
    fr[4] = hi8(a8, a9); fr[5] = hi8(aa, ab); fr[6] = hi8(ac, ad); fr[7] = hi8(ae, af);
}

// ---------------- tagged-exchange two-layer recurrence ----------------------
// 256 blocks x 256 threads, 1 block/CU (LDS 82KB). Blocks [0,128): layer 0,
// [128,256): layer 1 (consumes h0(k) same-k, 1-step-behind in wall time).
// Exchange: h{0,1}ex[4][B][H] tagged f32 (hi16 = exact bf16, lo16 = epoch+1).
// Per step k: poll per-wave flags (own layer >= k; other layer: L1 needs
// L0 >= k+1, L0 needs L1 >= k-3 for 4-deep buffer reuse) -> direct-to-frag
// tagged loads with verify+retry (sound without producer drains) -> MFMA ->
// one barrier (Rs parity-double-buffered) -> reduce+tanh -> tagged store +
// per-wave flag (no drain, no end barrier). All spins bounded.
template <int LAYER>
__device__ __forceinline__ void rnn_body(
    const ushort_t* __restrict__ xp, ushort_t* __restrict__ xq,
    unsigned* __restrict__ h0ex, unsigned* __restrict__ h1ex,
    const float* __restrict__ Wa, const float* __restrict__ Wb,
    const float* __restrict__ ba, const float* __restrict__ bb,
    int* __restrict__ bar, int gb, int cb,
    float (*__restrict__ Rs)[4][16][161]) {

    const int tid = threadIdx.x;
    const int lane = tid & 63;
    const int w = tid >> 6;
    const int q = lane >> 4;
    const int l16 = lane & 15;
    const int b0 = gb * 16;
    const int n0 = cb * 32;
    const int kb = w * 256;

    int* flL0 = bar + gb * 4096;        // 128 wave-flags @ 32-int stride
    int* flL1 = bar + (4 + gb) * 4096;
    int* flOwn = (LAYER == 0) ? flL0 : flL1;
    int* flOth = (LAYER == 0) ? flL1 : flL0;
    int* myflag = flOwn + ((cb * 4 + w) << 5);
    int* pA0 = flOwn + ((lane * 2) << 5);
    int* pA1 = flOwn + ((lane * 2 + 1) << 5);
    int* pB0 = flOth + ((lane * 2) << 5);
    int* pB1 = flOth + ((lane * 2 + 1) << 5);

    // loop-invariant weight fragments (land in AGPRs; proven round 1)
    bf16x8 wA[16], wB[16];
#pragma unroll
    for (int g = 0; g < 2; g++)
#pragma unroll
        for (int kk = 0; kk < 8; kk++) {
            size_t off = (size_t)(n0 + g * 16 + l16) * H_ + kb + kk * 32 + q * 8;
            wA[g * 8 + kk] = pack8(Wa + off);
            if (LAYER == 1) wB[g * 8 + kk] = pack8(Wb + off);
        }

    const int em = tid >> 4;        // output row 0..15
    const int en = (tid & 15) * 2;  // output col pair
    float bv0 = ba[n0 + en], bv1 = ba[n0 + en + 1];
    if (LAYER == 1) { bv0 += bb[n0 + en]; bv1 += bb[n0 + en + 1]; }

    for (int k = 0; k < 512; ++k) {
        // ---- L0: prefetch x-projection word (read-only GEMM output, plain)
        unsigned xw = 0;
        if (LAYER == 0) {
            const unsigned* xpp = (const unsigned*)(xp + (size_t)k * BH
                                  + (size_t)(b0 + em) * H_ + n0 + en);
            asm volatile("global_load_dword %0, %1, off" : "=&v"(xw) : "v"(xpp));
        }

        // ---- poll per-wave flags (4 per lane covers 2x128 flags per wave)
        {
            const int thrA = k;
            const int thrB = (LAYER == 0) ? (k - 3) : (k + 1);
            for (int spin = 0; ; ++spin) {
                int fa0, fa1, fb0, fb1;
                asm volatile(
                    "global_load_dword %0, %4, off sc0 sc1\n\t"
                    "global_load_dword %1, %5, off sc0 sc1\n\t"
                    "global_load_dword %2, %6, off sc0 sc1\n\t"
                    "global_load_dword %3, %7, off sc0 sc1\n\t"
                    "s_waitcnt vmcnt(0)"
                    : "=&v"(fa0), "=&v"(fa1), "=&v"(fb0), "=&v"(fb1)
                    : "v"(pA0), "v"(pA1), "v"(pB0), "v"(pB1)
                    : "memory");
                bool ok = (fa0 >= thrA) && (fa1 >= thrA) && (fb0 >= thrB) && (fb1 >= thrB);
                if (__ballot(ok) == ~0ull) break;
                if (spin > (1 << 14)) break;  // watchdog
            }
        }

        // ---- direct tagged fragment loads (verify+retry)
        bf16x8 fa[8], fb[8];
        if (LAYER == 0) {
            // A = h0(k-1): parity (k-1)&3, tag k
            const unsigned* ab = h0ex + (size_t)((k + 3) & 3) * BH
                               + (size_t)(b0 + l16) * H_ + kb + q * 8;
            load_verify16(ab, (unsigned)k, fa);
        } else {
            // A = h0(k): parity k&3, tag k+1
            const unsigned* ap = h0ex + (size_t)(k & 3) * BH
                               + (size_t)(b0 + l16) * H_ + kb + q * 8;
            load_verify16(ap, (unsigned)(k + 1), fa);
            // B = h1(k-1): parity (k-1)&3, tag k
            const unsigned* bp = h1ex + (size_t)((k + 3) & 3) * BH
                               + (size_t)(b0 + l16) * H_ + kb + q * 8;
            load_verify16(bp, (unsigned)k, fb);
        }

        // ---- MFMA: wave w covers K-slice [256w,+256), 2 col-groups
        f32x4 z = {0.f, 0.f, 0.f, 0.f};
        f32x4 acc0 = z, acc1 = z;
#pragma unroll
        for (int kk = 0; kk < 8; kk++) {
            acc0 = __builtin_amdgcn_mfma_f32_16x16x32_bf16(fa[kk], wA[kk], acc0, 0, 0, 0);
            acc1 = __builtin_amdgcn_mfma_f32_16x16x32_bf16(fa[kk], wA[8 + kk], acc1, 0, 0, 0);
        }
        if (LAYER == 1) {
#pragma unroll
            for (int kk = 0; kk < 8; kk++) {
                acc0 = __builtin_amdgcn_mfma_f32_16x16x32_bf16(fb[kk], wB[kk], acc0, 0, 0, 0);
                acc1 = __builtin_amdgcn_mfma_f32_16x16x32_bf16(fb[kk], wB[8 + kk], acc1, 0, 0, 0);
            }
        }
        const int pr = k & 1;  // Rs parity double-buffer: one barrier per step
#pragma unroll
        for (int rr = 0; rr < 4; rr++) {
            Rs[pr][w][q * 4 + rr][l16] = acc0[rr];
            Rs[pr][w][q * 4 + rr][16 + l16] = acc1[rr];
        }
        __syncthreads();

        // ---- reduce 4 K-slices + bias(+x) + tanh
        float s0 = Rs[pr][0][em][en] + Rs[pr][1][em][en] + Rs[pr][2][em][en] + Rs[pr][3][em][en];
        float s1 = Rs[pr][0][em][en + 1] + Rs[pr][1][em][en + 1]
                 + Rs[pr][2][em][en + 1] + Rs[pr][3][em][en + 1];
        if (LAYER == 0) {
            s0 += bf2f((ushort_t)(xw & 0xffff));
            s1 += bf2f((ushort_t)(xw >> 16));
        }
        s0 += bv0; s1 += bv1;
        unsigned u0 = f2bf(tanhf(s0)), u1 = f2bf(tanhf(s1));

        // ---- tagged exchange store (no drain needed: tags self-validate)
        unsigned tg = (unsigned)(k + 1);
        unsigned long long pv = (unsigned long long)(((unsigned)u0 << 16) | tg)
                              | ((unsigned long long)(((unsigned)u1 << 16) | tg) << 32);
        unsigned* exdst = (LAYER == 0 ? h0ex : h1ex) + (size_t)(k & 3) * BH
                        + (size_t)(b0 + em) * H_ + n0 + en;
        asm volatile("global_store_dwordx2 %0, %1, off sc0 sc1"
                     :: "v"(exdst), "v"(pv) : "memory");
        if (LAYER == 1) {  // bf16 history for the output GEMM (plain store)
            *(unsigned*)(xq + (size_t)k * BH + (size_t)(b0 + em) * H_ + n0 + en)
                = (unsigned)u0 | ((unsigned)u1 << 16);
        }
        // ---- per-wave flag, issued right after this wave's stores (no drain;
        // landing disorder is covered by consumer tag-verify)
        if (lane == 0) {
            int fv = k + 1;
            asm volatile("global_store_dword %0, %1, off sc0 sc1"
                         :: "v"(myflag), "v"(fv) : "memory");
        }
    }
}

__launch_bounds__(256, 1)
__global__ void rnn_tag(const ushort_t* __restrict__ xp, ushort_t* __restrict__ xq,
                        unsigned* __restrict__ h0ex, unsigned* __restrict__ h1ex,
                        const float* __restrict__ W_hh0, const float* __restrict__ b_hh0,
                        const float* __restrict__ W_ih1, const float* __restrict__ W_hh1,
                        const float* __restrict__ b_ih1, const float* __restrict__ b_hh1,
                        int* __restrict__ bar) {
    // 82432B LDS: also forces 1 block/CU (>80KB) so all 256 blocks co-resident
    __shared__ float Rs[2][4][16][161];
    const int gb = (blockIdx.x >> 5) & 3;
    const int cb = blockIdx.x & 31;
    if (blockIdx.x < 128)
        rnn_body<0>(xp, xq, h0ex, h1ex, W_hh0, W_hh0, b_hh0, b_hh0, bar, gb, cb, Rs);
    else
        rnn_body<1>(xp, xq, h0ex, h1ex, W_ih1, W_hh1, b_ih1, b_hh1, bar, gb, cb, Rs);
}

// ---------------------------------------------------------------- launch ----
extern "C" void kernel_launch(void* const* d_in, const int* in_sizes, int n_in,
                              void* d_out, int out_size, void* d_ws, size_t ws_size,
                              hipStream_t stream) {
    (void)in_sizes; (void)n_in; (void)out_size; (void)ws_size;
    const float* emb   = (const float*)d_in[0];
    const float* h0    = (const float*)d_in[1];
    const float* W_ih0 = (const float*)d_in[2];
    const float* b_ih0 = (const float*)d_in[3];
    const float* W_ih1 = (const float*)d_in[4];
    const float* b_ih1 = (const float*)d_in[5];
    const float* W_hh0 = (const float*)d_in[6];
    const float* b_hh0 = (const float*)d_in[7];
    const float* W_hh1 = (const float*)d_in[8];
    const float* b_hh1 = (const float*)d_in[9];
    const float* W_out = (const float*)d_in[10];
    const float* b_out = (const float*)d_in[11];
    float* out = (float*)d_out;

    char* ws = (char*)d_ws;
    int*      bar  = (int*)ws;                          // 32768 ints = 128KB
    unsigned* h0ex = (unsigned*)(ws + 131072);          // 4*BH u32 = 1MB
    unsigned* h1ex = (unsigned*)(ws + 131072 + 1048576);// 1MB
    ushort_t* xp   = (ushort_t*)(ws + 131072 + 2097152);// (T,B,H) bf16 xproj
    ushort_t* xq   = xp + (size_t)T_ * BH;              // (T,B,H) bf16 h1 hist

    prep_kernel<<<256, 256, 0, stream>>>(h0, h0ex, h1ex, bar);

    // xp = emb . W_ih0^T + b_ih0   (stored (T,B,H); read-only afterwards)
    gemm_bt<0><<<dim3(H_ / 128, (B_ * T_) / 128), 256, 0, stream>>>(
        emb, W_ih0, b_ih0, xp, H_, E_);

    // tagged-exchange recurrence, both layers concurrent
    rnn_tag<<<256, 256, 0, stream>>>(xp, xq, h0ex, h1ex,
                                     W_hh0, b_hh0, W_ih1, W_hh1, b_ih1, b_hh1, bar);

    // out = h1_all . W_out^T + b_out   ((B,T,O) fp32)
    gemm_bt<2><<<dim3(O_ / 128, (B_ * T_) / 128), 256, 0, stream>>>(
        xq, W_out, b_out, out, O_, H_);
}

// Round 7
// 1772.287 us; speedup vs baseline: 2.4076x; 2.4076x over previous
//
#include <hip/hip_runtime.h>
#include <cmath>

#define B_ 64
#define T_ 512
#define E_ 512
#define H_ 1024
#define O_ 512
#define BH (B_ * H_)
#define HSTRIDE 1160  // LDS row stride (elems)

typedef unsigned short ushort_t;
typedef __bf16 bf16x8 __attribute__((ext_vector_type(8)));
typedef float f32x4 __attribute__((ext_vector_type(4)));

__device__ __forceinline__ ushort_t f2bf(float f) {
    union { float f; unsigned int u; } x; x.f = f;
    unsigned int r = x.u + 0x7fffu + ((x.u >> 16) & 1u);
    return (ushort_t)(r >> 16);
}
__device__ __forceinline__ float bf2f(ushort_t u) {
    union { unsigned int u; float f; } x; x.u = ((unsigned int)u) << 16;
    return x.f;
}
__device__ __forceinline__ uint4 pack8bf(float4 v0, float4 v1) {
    uint4 pk;
    pk.x = (unsigned)f2bf(v0.x) | ((unsigned)f2bf(v0.y) << 16);
    pk.y = (unsigned)f2bf(v0.z) | ((unsigned)f2bf(v0.w) << 16);
    pk.z = (unsigned)f2bf(v1.x) | ((unsigned)f2bf(v1.y) << 16);
    pk.w = (unsigned)f2bf(v1.z) | ((unsigned)f2bf(v1.w) << 16);
    return pk;
}
__device__ __forceinline__ bf16x8 pack8(const float* src) {
    float4 v0 = *(const float4*)src;
    float4 v1 = *(const float4*)(src + 4);
    union { uint4 u; bf16x8 b; } c;
    c.u = pack8bf(v0, v1);
    return c.b;
}

// ---------------------------------------------------------------- prep ------
__global__ void prep_kernel(const float* __restrict__ h0, ushort_t* __restrict__ hinit,
                            int* __restrict__ bar) {
    int i = blockIdx.x * blockDim.x + threadIdx.x;
    if (i < 8192) bar[i] = 0;   // flag arrays: 2 layers x 4 groups x 32 flags x 32-int stride
    if (i < 2 * BH) hinit[i] = f2bf(h0[i]);
}

// ------------------------------------------------ big GEMM: C = A*W^T + b ---
// MODE 0: A fp32 (emb, (B,T,E), row r=t*64+b -> emb row (b,t)), out bf16 direct rows
// MODE 2: A bf16 direct rows, out fp32 remapped row r=t*64+b -> out row (b,t)
template <int MODE>
__launch_bounds__(256)
__global__ void gemm_bt(const void* __restrict__ Ap, const float* __restrict__ Wp,
                        const float* __restrict__ bias, void* __restrict__ outp,
                        int N, int K) {
    __shared__ __align__(16) ushort_t As[128 * 72];
    __shared__ __align__(16) ushort_t Bs[128 * 72];
    const int tid = threadIdx.x;
    const int lane = tid & 63;
    const int w = tid >> 6;
    const int wm = (w >> 1) * 64;
    const int wn = (w & 1) * 64;
    const int q = lane >> 4;
    const int l16 = lane & 15;
    const int m0 = blockIdx.y * 128;
    const int n0 = blockIdx.x * 128;

    const float*    Af = (const float*)Ap;
    const ushort_t* Ab = (const ushort_t*)Ap;

    f32x4 zero = {0.f, 0.f, 0.f, 0.f};
    f32x4 acc[4][4];
#pragma unroll
    for (int i = 0; i < 4; i++)
#pragma unroll
        for (int j = 0; j < 4; j++) acc[i][j] = zero;

    for (int k0 = 0; k0 < K; k0 += 64) {
#pragma unroll
        for (int it = 0; it < 4; it++) {
            int task = tid + it * 256;
            int row = task >> 3, seg = task & 7;
            if (MODE == 0) {
                int Ra = m0 + row;
                const float* src = Af + (size_t)((Ra & 63) * T_ + (Ra >> 6)) * K + k0 + seg * 8;
                float4 v0 = *(const float4*)src;
                float4 v1 = *(const float4*)(src + 4);
                *(uint4*)&As[row * 72 + seg * 8] = pack8bf(v0, v1);
            } else {
                const ushort_t* src = Ab + (size_t)(m0 + row) * K + k0 + seg * 8;
                *(uint4*)&As[row * 72 + seg * 8] = *(const uint4*)src;
            }
            const float* wsrc = Wp + (size_t)(n0 + row) * K + k0 + seg * 8;
            float4 w0 = *(const float4*)wsrc;
            float4 w1 = *(const float4*)(wsrc + 4);
            *(uint4*)&Bs[row * 72 + seg * 8] = pack8bf(w0, w1);
        }
        __syncthreads();
#pragma unroll
        for (int ks = 0; ks < 64; ks += 32) {
            bf16x8 af[4], bfr[4];
#pragma unroll
            for (int i = 0; i < 4; i++)
                af[i] = *(const bf16x8*)&As[(wm + i * 16 + l16) * 72 + ks + q * 8];
#pragma unroll
            for (int j = 0; j < 4; j++)
                bfr[j] = *(const bf16x8*)&Bs[(wn + j * 16 + l16) * 72 + ks + q * 8];
#pragma unroll
            for (int i = 0; i < 4; i++)
#pragma unroll
                for (int j = 0; j < 4; j++)
                    acc[i][j] = __builtin_amdgcn_mfma_f32_16x16x32_bf16(af[i], bfr[j], acc[i][j], 0, 0, 0);
        }
        __syncthreads();
    }

#pragma unroll
    for (int j = 0; j < 4; j++) {
        int C = n0 + wn + j * 16 + l16;
        float bv = bias[C];
#pragma unroll
        for (int i = 0; i < 4; i++) {
#pragma unroll
            for (int r = 0; r < 4; r++) {
                int R = m0 + wm + i * 16 + q * 4 + r;
                float v = acc[i][j][r] + bv;
                if (MODE == 2) {
                    ((float*)outp)[(size_t)((R & 63) * T_ + (R >> 6)) * N + C] = v;
                } else {
                    ((ushort_t*)outp)[(size_t)R * N + C] = f2bf(v);
                }
            }
        }
    }
}

// -------------------- fused two-layer persistent recurrence (1-step skew) ---
// 256 blocks x 256 threads, 1 block/CU (LDS-limited), all co-resident.
// Blocks [0,128): layer 0.  Blocks [128,256): layer 1, lagging.
// R1-proven protocol; R7 delta: layer-1 issues its h0(k) loads under the
// (always-satisfied, L0 runs ahead) L0 gate, hiding their latency beneath the
// own-h1-flag poll, so only the 32KB h1 load sits on the critical path.
template <int LAYER>
__device__ __forceinline__ void rnn_body(
    ushort_t* __restrict__ xall, const ushort_t* __restrict__ xsrc,
    const ushort_t* __restrict__ hin,
    const float* __restrict__ Wa, const float* __restrict__ Wb,
    const float* __restrict__ ba, const float* __restrict__ bb,
    int* __restrict__ bar,
    ushort_t* __restrict__ Hs0, ushort_t* __restrict__ Hs1,
    float (*__restrict__ Rs)[16][33]) {
    (void)xsrc;

    const int tid = threadIdx.x;
    const int lane = tid & 63;
    const int w = tid >> 6;
    const int q = lane >> 4;
    const int l16 = lane & 15;
    const int gb = (blockIdx.x >> 5) & 3;
    const int cb = blockIdx.x & 31;
    const int b0 = gb * 16;
    const int n0 = cb * 32;
    int* flags   = bar + (LAYER * 4 + gb) * 1024;  // own layer's flag group
    int* flagsrc = bar + gb * 1024;                // layer-0 flags (for LAYER 1)
    int* myflag  = flags + (cb << 5);
    int* pollown = flags + ((lane & 31) << 5);
    int* pollsrc = flagsrc + ((lane & 31) << 5);

    // ---- register B-fragments (loop-invariant weights)
    bf16x8 wA[16], wB[16];
#pragma unroll
    for (int g = 0; g < 2; g++)
#pragma unroll
        for (int kk = 0; kk < 8; kk++) {
            size_t off = (size_t)(n0 + g * 16 + l16) * H_ + w * 256 + kk * 32 + q * 8;
            wA[g * 8 + kk] = pack8(Wa + off);
            if (LAYER == 1) wB[g * 8 + kk] = pack8(Wb + off);
        }

    const int em = tid >> 4;
    const int en = (tid & 15) * 2;
    float bv0 = ba[n0 + en], bv1 = ba[n0 + en + 1];
    if (LAYER == 1) { bv0 += bb[n0 + en]; bv1 += bb[n0 + en + 1]; }

    const int rbase2 = (tid >> 7) * 2;  // 0 or 2
    const int seg = tid & 127;

    for (int r = 0; r < 512; r++) {
        unsigned xw = 0;
        uint4 d0, d1, d2, d3, d4, d5, d6, d7;
        uint4 e0, e1, e2, e3, e4, e5, e6, e7;

        if (LAYER == 0) {
            // ---- prefetch own xp word BEFORE the poll (prior-dispatch GEMM
            // output; plain cached — R0-proven. Later readers of these
            // addresses use sc0 sc1, so the cached pre-overwrite line is
            // never consumed stale.)
            const ushort_t* xaddr = xall + (size_t)r * BH + (size_t)(b0 + em) * H_ + n0 + en;
            asm volatile("global_load_dword %0, %1, off"
                         : "=&v"(xw) : "v"(xaddr) : "memory");

            // ---- own-chain flag wait (bounded)
            if (r > 0) {
                int spin = 0;
                while (true) {
                    int v;
                    asm volatile("global_load_dword %0, %1, off sc0 sc1\n\ts_waitcnt vmcnt(0)"
                                 : "=&v"(v) : "v"(pollown) : "memory");
                    if (__ballot(v >= r) == ~0ull) break;
                    if (++spin > (1 << 18)) break;
                }
            }

            // ---- critical-path load: h-state rows (32KB), LLC-coherent
            const ushort_t* s1 = (r == 0) ? hin : (xall + (size_t)(r - 1) * BH);
            const ushort_t* c0 = s1 + (size_t)(b0 + rbase2) * H_ + seg * 8;
            const ushort_t* c1 = c0 + 4 * H_;
            const ushort_t* c2 = c0 + 8 * H_;
            const ushort_t* c3 = c0 + 12 * H_;
            asm volatile(
                "global_load_dwordx4 %0, %8, off sc0 sc1\n\t"
                "global_load_dwordx4 %1, %8, off offset:2048 sc0 sc1\n\t"
                "global_load_dwordx4 %2, %9, off sc0 sc1\n\t"
                "global_load_dwordx4 %3, %9, off offset:2048 sc0 sc1\n\t"
                "global_load_dwordx4 %4, %10, off sc0 sc1\n\t"
                "global_load_dwordx4 %5, %10, off offset:2048 sc0 sc1\n\t"
                "global_load_dwordx4 %6, %11, off sc0 sc1\n\t"
                "global_load_dwordx4 %7, %11, off offset:2048 sc0 sc1\n\t"
                "s_waitcnt vmcnt(0)"
                : "=&v"(e0), "=&v"(e1), "=&v"(e2), "=&v"(e3),
                  "=&v"(e4), "=&v"(e5), "=&v"(e6), "=&v"(e7)
                : "v"(c0), "v"(c1), "v"(c2), "v"(c3)
                : "memory");
        } else {
            // ---- L0 gate (L0 drifts ahead -> normally instant), bounded
            {
                int spin = 0;
                while (true) {
                    int v;
                    asm volatile("global_load_dword %0, %1, off sc0 sc1\n\ts_waitcnt vmcnt(0)"
                                 : "=&v"(v) : "v"(pollsrc) : "memory");
                    if (__ballot(v >= r + 1) == ~0ull) break;
                    if (++spin > (1 << 18)) break;
                }
            }
            // ---- issue h0(r) loads NOW, no wait: latency hides under the
            // own-flag poll below (its vmcnt(0) also completes these)
            const ushort_t* a0 = xsrc + (size_t)r * BH + (size_t)(b0 + rbase2) * H_ + seg * 8;
            const ushort_t* a1 = a0 + 4 * H_;
            const ushort_t* a2 = a0 + 8 * H_;
            const ushort_t* a3 = a0 + 12 * H_;
            asm volatile(
                "global_load_dwordx4 %0, %8, off sc0 sc1\n\t"
                "global_load_dwordx4 %1, %8, off offset:2048 sc0 sc1\n\t"
                "global_load_dwordx4 %2, %9, off sc0 sc1\n\t"
                "global_load_dwordx4 %3, %9, off offset:2048 sc0 sc1\n\t"
                "global_load_dwordx4 %4, %10, off sc0 sc1\n\t"
                "global_load_dwordx4 %5, %10, off offset:2048 sc0 sc1\n\t"
                "global_load_dwordx4 %6, %11, off sc0 sc1\n\t"
                "global_load_dwordx4 %7, %11, off offset:2048 sc0 sc1"
                : "=&v"(d0), "=&v"(d1), "=&v"(d2), "=&v"(d3),
                  "=&v"(d4), "=&v"(d5), "=&v"(d6), "=&v"(d7)
                : "v"(a0), "v"(a1), "v"(a2), "v"(a3)
                : "memory");

            // ---- own-chain (h1) flag wait (bounded)
            if (r > 0) {
                int spin = 0;
                while (true) {
                    int v;
                    asm volatile("global_load_dword %0, %1, off sc0 sc1\n\ts_waitcnt vmcnt(0)"
                                 : "=&v"(v) : "v"(pollown) : "memory");
                    if (__ballot(v >= r) == ~0ull) break;
                    if (++spin > (1 << 18)) break;
                }
            }

            // ---- critical-path load: h1(r-1) rows (32KB), LLC-coherent
            const ushort_t* s1 = (r == 0) ? hin : (xall + (size_t)(r - 1) * BH);
            const ushort_t* c0 = s1 + (size_t)(b0 + rbase2) * H_ + seg * 8;
            const ushort_t* c1 = c0 + 4 * H_;
            const ushort_t* c2 = c0 + 8 * H_;
            const ushort_t* c3 = c0 + 12 * H_;
            asm volatile(
                "global_load_dwordx4 %0, %8, off sc0 sc1\n\t"
                "global_load_dwordx4 %1, %8, off offset:2048 sc0 sc1\n\t"
                "global_load_dwordx4 %2, %9, off sc0 sc1\n\t"
                "global_load_dwordx4 %3, %9, off offset:2048 sc0 sc1\n\t"
                "global_load_dwordx4 %4, %10, off sc0 sc1\n\t"
                "global_load_dwordx4 %5, %10, off offset:2048 sc0 sc1\n\t"
                "global_load_dwordx4 %6, %11, off sc0 sc1\n\t"
                "global_load_dwordx4 %7, %11, off offset:2048 sc0 sc1\n\t"
                "s_waitcnt vmcnt(0)"
                : "=&v"(e0), "=&v"(e1), "=&v"(e2), "=&v"(e3),
                  "=&v"(e4), "=&v"(e5), "=&v"(e6), "=&v"(e7)
                : "v"(c0), "v"(c1), "v"(c2), "v"(c3)
                : "memory");
            __builtin_amdgcn_sched_barrier(0);

            *(uint4*)&Hs0[(rbase2 + 0) * HSTRIDE + seg * 8] = d0;
            *(uint4*)&Hs0[(rbase2 + 1) * HSTRIDE + seg * 8] = d1;
            *(uint4*)&Hs0[(rbase2 + 4) * HSTRIDE + seg * 8] = d2;
            *(uint4*)&Hs0[(rbase2 + 5) * HSTRIDE + seg * 8] = d3;
            *(uint4*)&Hs0[(rbase2 + 8) * HSTRIDE + seg * 8] = d4;
            *(uint4*)&Hs0[(rbase2 + 9) * HSTRIDE + seg * 8] = d5;
            *(uint4*)&Hs0[(rbase2 + 12) * HSTRIDE + seg * 8] = d6;
            *(uint4*)&Hs0[(rbase2 + 13) * HSTRIDE + seg * 8] = d7;
        }
        *(uint4*)&Hs1[(rbase2 + 0) * HSTRIDE + seg * 8] = e0;
        *(uint4*)&Hs1[(rbase2 + 1) * HSTRIDE + seg * 8] = e1;
        *(uint4*)&Hs1[(rbase2 + 4) * HSTRIDE + seg * 8] = e2;
        *(uint4*)&Hs1[(rbase2 + 5) * HSTRIDE + seg * 8] = e3;
        *(uint4*)&Hs1[(rbase2 + 8) * HSTRIDE + seg * 8] = e4;
        *(uint4*)&Hs1[(rbase2 + 9) * HSTRIDE + seg * 8] = e5;
        *(uint4*)&Hs1[(rbase2 + 12) * HSTRIDE + seg * 8] = e6;
        *(uint4*)&Hs1[(rbase2 + 13) * HSTRIDE + seg * 8] = e7;
        __syncthreads();

        // ---- MFMA: wave w covers K slice [256w,+256), both 16-col groups
        f32x4 acc0 = {0.f, 0.f, 0.f, 0.f};
        f32x4 acc1 = {0.f, 0.f, 0.f, 0.f};
        const int kb = w * 256;
        if (LAYER == 1) {
#pragma unroll
            for (int kk = 0; kk < 8; kk++) {
                bf16x8 a = *(const bf16x8*)&Hs0[l16 * HSTRIDE + kb + kk * 32 + q * 8];
                acc0 = __builtin_amdgcn_mfma_f32_16x16x32_bf16(a, wA[kk], acc0, 0, 0, 0);
                acc1 = __builtin_amdgcn_mfma_f32_16x16x32_bf16(a, wA[8 + kk], acc1, 0, 0, 0);
            }
#pragma unroll
            for (int kk = 0; kk < 8; kk++) {
                bf16x8 a = *(const bf16x8*)&Hs1[l16 * HSTRIDE + kb + kk * 32 + q * 8];
                acc0 = __builtin_amdgcn_mfma_f32_16x16x32_bf16(a, wB[kk], acc0, 0, 0, 0);
                acc1 = __builtin_amdgcn_mfma_f32_16x16x32_bf16(a, wB[8 + kk], acc1, 0, 0, 0);
            }
        } else {
#pragma unroll
            for (int kk = 0; kk < 8; kk++) {
                bf16x8 a = *(const bf16x8*)&Hs1[l16 * HSTRIDE + kb + kk * 32 + q * 8];
                acc0 = __builtin_amdgcn_mfma_f32_16x16x32_bf16(a, wA[kk], acc0, 0, 0, 0);
                acc1 = __builtin_amdgcn_mfma_f32_16x16x32_bf16(a, wA[8 + kk], acc1, 0, 0, 0);
            }
        }
#pragma unroll
        for (int rr = 0; rr < 4; rr++) {
            Rs[w][q * 4 + rr][l16] = acc0[rr];
            Rs[w][q * 4 + rr][16 + l16] = acc1[rr];
        }
        __syncthreads();

        // ---- reduce 4 waves + tanh + coherent store of a col pair
        {
            float sA = Rs[0][em][en] + Rs[1][em][en] + Rs[2][em][en] + Rs[3][em][en];
            float sB = Rs[0][em][en + 1] + Rs[1][em][en + 1] + Rs[2][em][en + 1] + Rs[3][em][en + 1];
            ushort_t* dst = xall + (size_t)r * BH + (size_t)(b0 + em) * H_ + n0 + en;
            if (LAYER == 0) {
                sA += bf2f((ushort_t)(xw & 0xffff));
                sB += bf2f((ushort_t)(xw >> 16));
            }
            sA += bv0;
            sB += bv1;
            unsigned pk = (unsigned)f2bf(tanhf(sA)) | ((unsigned)f2bf(tanhf(sB)) << 16);
            __hip_atomic_store((unsigned*)dst, pk, __ATOMIC_RELAXED, __HIP_MEMORY_SCOPE_SYSTEM);
        }

        // ---- signal: drain stores, then publish this block's flag.
        // Layer 0 must publish r=511 too (layer 1 consumes h0(511)).
        if (LAYER == 0 || r < 511) {
            __syncthreads();  // vmcnt(0) drain: h stores LLC-visible before flag
            if (tid == 0)
                __hip_atomic_store(myflag, r + 1, __ATOMIC_RELAXED, __HIP_MEMORY_SCOPE_SYSTEM);
        }
    }
}

__launch_bounds__(256, 1)
__global__ void rnn_fused(ushort_t* __restrict__ x0, ushort_t* __restrict__ x1,
                          const ushort_t* __restrict__ hinit,
                          const float* __restrict__ W_hh0, const float* __restrict__ b_hh0,
                          const float* __restrict__ W_ih1, const float* __restrict__ W_hh1,
                          const float* __restrict__ b_ih1, const float* __restrict__ b_hh1,
                          int* __restrict__ bar) {
    __shared__ __align__(16) ushort_t Hs0[16 * HSTRIDE];  // x-source rows (layer 1)
    __shared__ __align__(16) ushort_t Hs1[16 * HSTRIDE];  // recurrent-state rows
    __shared__ float Rs[4][16][33];
    if (blockIdx.x < 128) {
        rnn_body<0>(x0, (const ushort_t*)nullptr, hinit,
                    W_hh0, W_hh0, b_hh0, b_hh0, bar, Hs0, Hs1, Rs);
    } else {
        rnn_body<1>(x1, x0, hinit + BH,
                    W_ih1, W_hh1, b_ih1, b_hh1, bar, Hs0, Hs1, Rs);
    }
}

// ---------------------------------------------------------------- launch ----
extern "C" void kernel_launch(void* const* d_in, const int* in_sizes, int n_in,
                              void* d_out, int out_size, void* d_ws, size_t ws_size,
                              hipStream_t stream) {
    (void)in_sizes; (void)n_in; (void)out_size; (void)ws_size;
    const float* emb   = (const float*)d_in[0];
    const float* h0    = (const float*)d_in[1];
    const float* W_ih0 = (const float*)d_in[2];
    const float* b_ih0 = (const float*)d_in[3];
    const float* W_ih1 = (const float*)d_in[4];
    const float* b_ih1 = (const float*)d_in[5];
    const float* W_hh0 = (const float*)d_in[6];
    const float* b_hh0 = (const float*)d_in[7];
    const float* W_hh1 = (const float*)d_in[8];
    const float* b_hh1 = (const float*)d_in[9];
    const float* W_out = (const float*)d_in[10];
    const float* b_out = (const float*)d_in[11];
    float* out = (float*)d_out;

    char* ws = (char*)d_ws;
    int*      bar   = (int*)ws;                      // flag arrays (8192 ints)
    ushort_t* hinit = (ushort_t*)(ws + 65536);       // 2*B*H bf16
    ushort_t* xp    = (ushort_t*)(ws + 65536 + 2 * BH * 2);  // (T,B,H) bf16: x0 -> h0
    ushort_t* xq    = xp + (size_t)T_ * BH;                  // (T,B,H) bf16: h1

    prep_kernel<<<512, 256, 0, stream>>>(h0, hinit, bar);

    // xp = emb . W_ih0^T + b_ih0   (stored (T,B,H))
    gemm_bt<0><<<dim3(H_ / 128, (B_ * T_) / 128), 256, 0, stream>>>(
        emb, W_ih0, b_ih0, xp, H_, E_);

    // fused: layer 0 (xp := h0_all in place) || layer 1 (xq := h1_all),
    // layer 1 lags, consuming h0(r) via layer-0 flags (prefetch-overlapped)
    rnn_fused<<<256, 256, 0, stream>>>(xp, xq, hinit,
                                       W_hh0, b_hh0, W_ih1, W_hh1, b_ih1, b_hh1, bar);

    // out = h1_all . W_out^T + b_out   ((B,T,O) fp32)
    gemm_bt<2><<<dim3(O_ / 128, (B_ * T_) / 128), 256, 0, stream>>>(
        xq, W_out, b_out, out, O_, H_);
}